// Round 12
// baseline (88.564 us; speedup 1.0000x reference)
//
#include <hip/hip_runtime.h>
#include <hip/hip_bf16.h>

#define B_ROWS 131072
#define H 128
#define SLAB 16
#define NSLAB 16                 // 256 rows per block strip
#define NBLK 512

typedef __bf16 bf16x8 __attribute__((ext_vector_type(8)));
typedef float f32x4 __attribute__((ext_vector_type(4)));

#define LOG2E 1.4426950408889634f

__device__ __forceinline__ float fast_sigmoid(float v) {
    return __builtin_amdgcn_rcpf(1.0f + __builtin_amdgcn_exp2f(-LOG2E * v));
}
__device__ __forceinline__ float fast_tanh(float v) {
    return 1.0f - 2.0f * __builtin_amdgcn_rcpf(1.0f + __builtin_amdgcn_exp2f(2.0f * LOG2E * v));
}

struct WPtrs {
    const float* wx[4];
    const float* wh[4];
    const float* bx[4];
    const float* bh[4];
};

// Wcat[n][k]: n = gate*128 + unit, k in [0,256) = [X-k | h-k]. bsum[n] = bx+bh.
__global__ __launch_bounds__(256) void prep_weights(WPtrs p, __bf16* __restrict__ wcat,
                                                    float* __restrict__ bsum) {
    int n = blockIdx.x;
    int k = threadIdx.x;
    int g = n >> 7, r = n & 127;
    float v = (k < H) ? p.wx[g][r * H + k] : p.wh[g][r * H + (k - H)];
    wcat[n * 256 + k] = (__bf16)v;
    if (k == 0) bsum[n] = p.bx[g][r] + p.bh[g][r];
}

// 512 thr / 8 waves = all 128 units; B-operand register-resident (128 VGPR/lane).
// R11 lesson: without a fence the compiler SINKS the wreg loads into the K-loop
// (VGPR was 112, in-loop global B loads re-entangled the vmcnt FIFO). The
// asm memory clobber pins all 32 B loads before the main loop: a load cannot
// be moved past a clobber that may write its memory. K-loop = 1 ds_read + 4
// MFMA per kc, ZERO in-loop vmcnt ops -> stage prefetch never force-drained.
__global__ __launch_bounds__(512, 1) void lstm_fused(
    const float* __restrict__ X, const float* __restrict__ Hp, const float* __restrict__ Cp,
    const __bf16* __restrict__ Wcat, const float* __restrict__ Bsum,
    float* __restrict__ out)
{
    __shared__ char abuf[2][SLAB * 512];    // 2 x 8 KB bf16 [X|h] slab, XOR-swizzled

    const int t = threadIdx.x;
    const int lane = t & 63;
    const int wv = t >> 6;                  // 0..7: unit group
    const int l16 = lane & 15;
    const int kg = lane >> 4;               // 0..3
    const long base = (long)blockIdx.x * (SLAB * NSLAB);
    const long c_off = (long)B_ROWS * H;
    const int j = wv * 16 + l16;            // this lane's unit (all 4 gates)

    // ---- B -> registers, once (L2-resident Wcat), then PIN with a fence ----
    bf16x8 wreg[4][8];                      // 128 VGPR
    {
        const __bf16* wb = Wcat + (long)j * 256 + kg * 8;
#pragma unroll
        for (int g = 0; g < 4; ++g)
#pragma unroll
            for (int kc = 0; kc < 8; ++kc)
                wreg[g][kc] = *(const bf16x8*)(wb + g * (128 * 256) + kc * 32);
    }
    float bias[4];
#pragma unroll
    for (int g = 0; g < 4; ++g) bias[g] = Bsum[g * H + j];
    asm volatile("" ::: "memory");          // forbid sinking the wreg loads

    // staging map: thread t -> row t>>5 (0..15), 8-float group t&31 (0..15 X, 16..31 h)
    const int s_r = t >> 5;
    const int s_g8 = t & 31;

    auto stage_load = [&](float4* L, long srow) {
        const float* sp = (s_g8 < 16) ? (X + (srow + s_r) * H + s_g8 * 8)
                                      : (Hp + (srow + s_r) * H + (s_g8 - 16) * 8);
        L[0] = *(const float4*)sp;
        L[1] = *(const float4*)(sp + 4);
    };
    auto write_slab = [&](char* buf, const float4* W) {
        union { __bf16 e[8]; bf16x8 v; } u;
        float4 lo = W[0], hi = W[1];
        u.e[0] = (__bf16)lo.x; u.e[1] = (__bf16)lo.y;
        u.e[2] = (__bf16)lo.z; u.e[3] = (__bf16)lo.w;
        u.e[4] = (__bf16)hi.x; u.e[5] = (__bf16)hi.y;
        u.e[6] = (__bf16)hi.z; u.e[7] = (__bf16)hi.w;
        *(bf16x8*)(buf + s_r * 512 + ((s_g8 ^ (s_r & 7)) << 4)) = u.v;
    };
    auto load_cp = [&](float* c, long srow) {
#pragma unroll
        for (int r = 0; r < 4; ++r) c[r] = Cp[(srow + kg * 4 + r) * H + j];
    };

    float4 RA[2], RB[2];
    float cpv[4], cpn[4];

    // prologue: slab0 -> buf0; slab1 loads in flight
    stage_load(RB, base);
    load_cp(cpv, base);
    stage_load(RA, base + SLAB);
    write_slab(abuf[0], RB);                // auto vmcnt wait on RB only

#define BODY(S, W, L, BW, BC) {                                                   \
    const long srow = base + (long)(S) * SLAB;                                    \
    const long pn1 = ((S) + 1 < NSLAB) ? (S) + 1 : NSLAB - 1;                     \
    const long pn2 = ((S) + 2 < NSLAB) ? (S) + 2 : NSLAB - 1;                     \
    stage_load(L, base + pn2 * SLAB);                                             \
    load_cp(cpn, base + pn1 * SLAB);                                              \
    asm volatile("s_waitcnt lgkmcnt(0)\n\ts_barrier" ::: "memory");               \
    write_slab(abuf[BW], W);                                                      \
    const char* ac = abuf[BC];                                                    \
    f32x4 acc[4] = {};                                                            \
    _Pragma("unroll")                                                             \
    for (int kc = 0; kc < 8; ++kc) {                                              \
        int slot = ((kc * 4 + kg) ^ (l16 & 7)) << 4;                              \
        bf16x8 av = *(const bf16x8*)(ac + l16 * 512 + slot);                      \
        _Pragma("unroll")                                                         \
        for (int g = 0; g < 4; ++g)                                               \
            acc[g] = __builtin_amdgcn_mfma_f32_16x16x32_bf16(av, wreg[g][kc], acc[g], 0, 0, 0); \
    }                                                                             \
    _Pragma("unroll")                                                             \
    for (int r = 0; r < 4; ++r) {                                                 \
        long row = srow + kg * 4 + r;                                             \
        float fg = acc[0][r] + bias[0];                                           \
        float ig = acc[1][r] + bias[1];                                           \
        float cg = acc[2][r] + bias[2];                                           \
        float og = acc[3][r] + bias[3];                                           \
        float ft = fast_sigmoid(fg);                                              \
        float it = fast_sigmoid(ig);                                              \
        float cc = fast_tanh(cg);                                                 \
        float ot = fast_sigmoid(og);                                              \
        float ct = ft * cpv[r] + it * cc;                                         \
        float ht = ot * fast_tanh(ct);                                            \
        out[row * H + j] = ht;                                                    \
        out[c_off + row * H + j] = ct;                                            \
    }                                                                             \
    _Pragma("unroll")                                                             \
    for (int r = 0; r < 4; ++r) cpv[r] = cpn[r];                                  \
}

    for (int sp = 0; sp < NSLAB / 2; ++sp) {
        BODY(2 * sp,     RA, RB, 1, 0);     // write buf1 (slab 2sp+1), compute buf0
        BODY(2 * sp + 1, RB, RA, 0, 1);     // write buf0 (slab 2sp+2), compute buf1
    }
#undef BODY
}

extern "C" void kernel_launch(void* const* d_in, const int* in_sizes, int n_in,
                              void* d_out, int out_size, void* d_ws, size_t ws_size,
                              hipStream_t stream) {
    const float* X  = (const float*)d_in[0];
    const float* Hp = (const float*)d_in[1];
    const float* Cp = (const float*)d_in[2];
    WPtrs p;
    p.wx[0] = (const float*)d_in[3];  p.bx[0] = (const float*)d_in[4];
    p.wh[0] = (const float*)d_in[5];  p.bh[0] = (const float*)d_in[6];
    p.wx[1] = (const float*)d_in[7];  p.bx[1] = (const float*)d_in[8];
    p.wh[1] = (const float*)d_in[9];  p.bh[1] = (const float*)d_in[10];
    p.wx[2] = (const float*)d_in[11]; p.bx[2] = (const float*)d_in[12];
    p.wh[2] = (const float*)d_in[13]; p.bh[2] = (const float*)d_in[14];
    p.wx[3] = (const float*)d_in[15]; p.bx[3] = (const float*)d_in[16];
    p.wh[3] = (const float*)d_in[17]; p.bh[3] = (const float*)d_in[18];

    __bf16* wcat = (__bf16*)d_ws;
    float*  bsum = (float*)((char*)d_ws + 512 * 256 * 2);

    prep_weights<<<512, 256, 0, stream>>>(p, wcat, bsum);
    lstm_fused<<<NBLK, 512, 0, stream>>>(X, Hp, Cp, wcat, bsum, (float*)d_out);
}